// Round 9
// baseline (415.850 us; speedup 1.0000x reference)
//
#include <hip/hip_runtime.h>
#include <math.h>

typedef unsigned int uint;
typedef unsigned short ushort;

#define NROWS 65536
#define KCB   1024
#define DDIM  256
#define MARGIN 0.15f

// d_out layout (floats)
#define OUT_ZQ    0
#define OUT_LOSS  16777216
#define OUT_IDX   16777217
#define OUT_PERP  16842753
#define OUT_USAGE 16842754

typedef __attribute__((ext_vector_type(8))) short s16x8;
typedef __attribute__((ext_vector_type(4))) float f32x4;

__device__ __forceinline__ ushort bf16rne(float x) {
  uint u = __float_as_uint(x);
  return (ushort)((u + 0x7FFFu + ((u >> 16) & 1u)) >> 16);
}
__device__ __forceinline__ float bf2f(ushort h) {
  return __uint_as_float((uint)h << 16);
}

// ---------------------------------------------------------------------------
// Kernel 1: codebook = normalize(lb @ W.T) * 16 in fp64 (LDS-staged W);
// emits transposed fp64 (cb64T[j][k] for refine), fp32, and bf16-hi copy.
// (cl dropped in round 9 -- argmax uses z-exact x c-hi only.)
// ---------------------------------------------------------------------------
__global__ __launch_bounds__(256) void cb_kernel(const float* __restrict__ lb,
                                                 const float* __restrict__ W,
                                                 double* __restrict__ cb64T,
                                                 float* __restrict__ cb32,
                                                 double* __restrict__ c264,
                                                 ushort* __restrict__ ch) {
  const int k = blockIdx.x;
  const int t = threadIdx.x;
  __shared__ float lb_sh[256];
  __shared__ float W_sh[256 * 66];
  __shared__ double red[256];

  lb_sh[t] = lb[k * 256 + t];

  double acc = 0.0;
  for (int jt = 0; jt < 4; ++jt) {
    __syncthreads();
#pragma unroll
    for (int i = 0; i < 16; ++i) {
      int qid = t + 256 * i;
      int row = qid >> 4;
      int q   = qid & 15;
      float4 v = *(const float4*)&W[row * 256 + jt * 64 + q * 4];
      float* dst = &W_sh[row * 66 + q * 4];
      dst[0] = v.x; dst[1] = v.y; dst[2] = v.z; dst[3] = v.w;
    }
    __syncthreads();
#pragma unroll
    for (int jj = 0; jj < 64; ++jj) {
      acc += (double)lb_sh[jt * 64 + jj] * (double)W_sh[t * 66 + jj];
    }
  }

  red[t] = acc * acc;
  __syncthreads();
  for (int s = 128; s > 0; s >>= 1) {
    if (t < s) red[t] += red[t + s];
    __syncthreads();
  }
  double norm  = sqrt(red[0]);
  double scale = 16.0 / fmax(norm, 1e-12);
  double v     = acc * scale;
  cb64T[(size_t)t * 1024 + k] = v;        // transposed for refine
  float cf = (float)v;
  cb32[k * 256 + t] = cf;
  ch[k * 256 + t] = bf16rne(cf);

  __syncthreads();
  red[t] = v * v;
  __syncthreads();
  for (int s = 128; s > 0; s >>= 1) {
    if (t < s) red[t] += red[t + s];
    __syncthreads();
  }
  if (t == 0) c264[k] = red[0];
}

// ---------------------------------------------------------------------------
// Kernel 2: fused MFMA argmax + gather, 16x16x32 (round-9).
// score = (zh + zl) . ch  -- z exact via hi/lo registers, c rounded to bf16
// hi only. Error sigma ~0.025 => MARGIN 0.15 (6 sigma) + exact fp64 refine.
// Per step: LDS tile = 64 codes x 64 k (ch only, 8 KB), K-major layout
// [kc][q][row] (conflict-free, linear gload_lds dest), double-buffered,
// 64 steps total (16 nt x 4 kt2), 8 ds_read + 16 MFMA + 2 gload_lds / step.
// ---------------------------------------------------------------------------
__global__ __launch_bounds__(256, 4) void argmax_mfma(const float* __restrict__ z,
                                                      const ushort* __restrict__ ch,
                                                      const float* __restrict__ cb32,
                                                      float* __restrict__ out_idx,
                                                      int* __restrict__ idx_int,
                                                      int* __restrict__ flagc,
                                                      int* __restrict__ flagr,
                                                      float* __restrict__ zq,
                                                      double* __restrict__ msep,
                                                      int* __restrict__ counts) {
  const int t     = threadIdx.x;
  const int lane  = t & 63;
  const int w     = t >> 6;
  const int ra    = lane & 15;     // z-row within wave
  const int q4    = lane >> 4;     // K-quarter (8 bf16 each)
  const int mtile = blockIdx.x;

  __shared__ alignas(128) char cbuf[2][8192];
  __shared__ int    sidx[64];
  __shared__ double partial[4];

  // ---- z fragments: one z-row per lane, fp32 -> bf16 hi/lo in-register ----
  s16x8 zh[8], zl[8];
  const int zrow = mtile * 64 + w * 16 + ra;
#pragma unroll
  for (int c = 0; c < 8; ++c) {
    const float* zp = &z[(size_t)zrow * 256 + c * 32 + q4 * 8];
    float4 f0 = *(const float4*)zp;
    float4 f1 = *(const float4*)(zp + 4);
    float xs[8] = {f0.x, f0.y, f0.z, f0.w, f1.x, f1.y, f1.z, f1.w};
#pragma unroll
    for (int e = 0; e < 8; ++e) {
      ushort hh = bf16rne(xs[e]);
      zh[c][e] = (short)hh;
      zl[c][e] = (short)bf16rne(xs[e] - bf2f(hh));
    }
  }

  // ---- staging: 512 slots of 16B; slot s: kc=s>>8, q=(s>>6)&3, row=s&63.
  //      Linear LDS dest (wave-uniform base), per-lane global source. ----
  auto stage = [&](int buf, int nt, int kt2) {
#pragma unroll
    for (int j = 0; j < 2; ++j) {
      int s   = w * 128 + j * 64 + lane;
      int kc  = s >> 8;
      int q   = (s >> 6) & 3;
      int row = s & 63;
      const ushort* src = ch + (size_t)(nt * 64 + row) * 256 + kt2 * 64 + kc * 32 + q * 8;
      __builtin_amdgcn_global_load_lds(
          (const __attribute__((address_space(1))) void*)src,
          (__attribute__((address_space(3))) void*)(&cbuf[buf][0] + (w * 128 + j * 64) * 16),
          16, 0, 0);
    }
  };

  float m1 = -3.0e38f, m2 = -3.0e38f;
  int   i1 = 0;

  stage(0, 0, 0);
  __syncthreads();

#pragma unroll 1
  for (int nt = 0; nt < 16; ++nt) {
    f32x4 acc[4] = {f32x4(0.0f), f32x4(0.0f), f32x4(0.0f), f32x4(0.0f)};
#pragma unroll
    for (int kt2 = 0; kt2 < 4; ++kt2) {
      const int cur = (nt * 4 + kt2) & 1;
      if (kt2 < 3)      stage(cur ^ 1, nt, kt2 + 1);
      else if (nt < 15) stage(cur ^ 1, nt + 1, 0);

      const char* cbb = &cbuf[cur][0];
#pragma unroll
      for (int kc = 0; kc < 2; ++kc) {
        const s16x8 bh = zh[kt2 * 2 + kc];
        const s16x8 bl = zl[kt2 * 2 + kc];
#pragma unroll
        for (int cg = 0; cg < 4; ++cg) {
          s16x8 a = *(const s16x8*)(cbb + kc * 4096 + q4 * 1024 + (cg * 16 + ra) * 16);
          acc[cg] = __builtin_amdgcn_mfma_f32_16x16x32_bf16(a, bh, acc[cg], 0, 0, 0);
          acc[cg] = __builtin_amdgcn_mfma_f32_16x16x32_bf16(a, bl, acc[cg], 0, 0, 0);
        }
      }
      __syncthreads();
    }

    // fold this nt's 64 codes into the lane's (m1, m2, i1).
    // D layout (m89/m91, round-8-verified): col = lane&15 = zrow;
    // code = cg*16 + q4*4 + j.
#pragma unroll
    for (int cg = 0; cg < 4; ++cg) {
#pragma unroll
      for (int j = 0; j < 4; ++j) {
        const int code = nt * 64 + cg * 16 + q4 * 4 + j;
        float v = acc[cg][j];
        if (v > m1) { m2 = m1; m1 = v; i1 = code; }
        else        { m2 = fmaxf(m2, v); }
      }
    }
  }

  // ---- cross-lane merge across the 4 K-quarter copies of each z-row ----
#pragma unroll
  for (int off = 16; off <= 32; off <<= 1) {
    float om1 = __shfl_xor(m1, off);
    float om2 = __shfl_xor(m2, off);
    int   oi1 = __shfl_xor(i1, off);
    if (om1 > m1 || (om1 == m1 && oi1 < i1)) {
      m2 = fmaxf(m1, om2); m1 = om1; i1 = oi1;
    } else {
      m2 = fmaxf(m2, om1);
    }
  }

  if (lane < 16) {
    const int row = mtile * 64 + w * 16 + lane;
    sidx[w * 16 + lane] = i1;
    idx_int[row] = i1;
    out_idx[row] = (float)i1;
    if (m1 - m2 < MARGIN) {
      int pos = atomicAdd(flagc, 1);
      flagr[pos] = row;
    }
  }
  __syncthreads();

  // ---- fused gather: z_q write, mse partial, counts ----
  double msum = 0.0;
  for (int rr = w; rr < 64; rr += 4) {
    const int code = sidx[rr];
    const int grow = mtile * 64 + rr;
    float4 c = *(const float4*)&cb32[(size_t)code * 256 + lane * 4];
    *(float4*)&zq[(size_t)grow * 256 + lane * 4] = c;
    float4 zr = *(const float4*)&z[(size_t)grow * 256 + lane * 4];
    double d;
    d = (double)c.x - (double)zr.x; msum += d * d;
    d = (double)c.y - (double)zr.y; msum += d * d;
    d = (double)c.z - (double)zr.z; msum += d * d;
    d = (double)c.w - (double)zr.w; msum += d * d;
    if (lane == 0) atomicAdd(&counts[code], 1);
  }
#pragma unroll
  for (int off = 32; off > 0; off >>= 1) msum += __shfl_xor(msum, off);
  if (lane == 0) partial[w] = msum;
  __syncthreads();
  if (t == 0) msep[mtile] = partial[0] + partial[1] + partial[2] + partial[3];
}

// ---------------------------------------------------------------------------
// Kernel 3: exact fp64 re-solve of flagged rows: thread t owns codes
// {t, t+256, t+512, t+768}; z-row broadcast from LDS; cb64T coalesced.
// Patches idx, z_q, counts, and mse delta for rows whose index changes.
// ---------------------------------------------------------------------------
__global__ __launch_bounds__(256) void refine_kernel(const float* __restrict__ z,
                                                     const double* __restrict__ cb64T,
                                                     const double* __restrict__ c264,
                                                     const float* __restrict__ cb32,
                                                     const int* __restrict__ flagc,
                                                     const int* __restrict__ flagr,
                                                     int* __restrict__ idx_int,
                                                     float* __restrict__ out_idx,
                                                     float* __restrict__ zq,
                                                     int* __restrict__ counts,
                                                     double* __restrict__ msedelta) {
  const int cnt = *flagc;
  const int t   = threadIdx.x;
  __shared__ double z_sh[256];
  __shared__ double rs[256];
  __shared__ int    ri[256];
  __shared__ int    shI, shO;
  __shared__ double red[256];

  for (int fi = blockIdx.x; fi < cnt; fi += gridDim.x) {
    const int row = flagr[fi];
    __syncthreads();
    z_sh[t] = (double)z[(size_t)row * DDIM + t];
    __syncthreads();

    double a0 = 0.0, a1 = 0.0, a2 = 0.0, a3 = 0.0;
    for (int j = 0; j < 256; ++j) {
      double zj = z_sh[j];
      const double* cp = &cb64T[(size_t)j * 1024 + t];
      a0 += zj * cp[0];
      a1 += zj * cp[256];
      a2 += zj * cp[512];
      a3 += zj * cp[768];
    }
    double b  = 2.0 * a0 - c264[t];       int bi_ = t;
    double s1 = 2.0 * a1 - c264[t + 256]; if (s1 > b) { b = s1; bi_ = t + 256; }
    double s2 = 2.0 * a2 - c264[t + 512]; if (s2 > b) { b = s2; bi_ = t + 512; }
    double s3 = 2.0 * a3 - c264[t + 768]; if (s3 > b) { b = s3; bi_ = t + 768; }
    rs[t] = b; ri[t] = bi_;
    __syncthreads();
    for (int s = 128; s > 0; s >>= 1) {
      if (t < s) {
        if (rs[t + s] > rs[t] || (rs[t + s] == rs[t] && ri[t + s] < ri[t])) {
          rs[t] = rs[t + s]; ri[t] = ri[t + s];
        }
      }
      __syncthreads();
    }
    if (t == 0) {
      int I = ri[0];
      shO = idx_int[row];
      shI = I;
      if (I != shO) {
        idx_int[row] = I;
        out_idx[row] = (float)I;
        atomicSub(&counts[shO], 1);
        atomicAdd(&counts[I], 1);
      }
    }
    __syncthreads();
    const int I = shI, O = shO;
    if (I != O) {
      float zz = z[(size_t)row * DDIM + t];
      float cn = cb32[(size_t)I * DDIM + t];
      float co = cb32[(size_t)O * DDIM + t];
      zq[(size_t)row * DDIM + t] = cn;
      double dn = (double)cn - (double)zz;
      double dd = (double)co - (double)zz;
      red[t] = dn * dn - dd * dd;
      __syncthreads();
      for (int s = 128; s > 0; s >>= 1) {
        if (t < s) red[t] += red[t + s];
        __syncthreads();
      }
      if (t == 0) atomicAdd(msedelta, red[0]);
    }
    __syncthreads();
  }
}

// ---------------------------------------------------------------------------
// Kernel 4: scalars -- vq_loss, perplexity, codebook_usage.
// ---------------------------------------------------------------------------
__global__ __launch_bounds__(256) void finalize_kernel(const int* __restrict__ counts,
                                                       const double* __restrict__ msep,
                                                       const double* __restrict__ msedelta,
                                                       float* __restrict__ out) {
  const int t = threadIdx.x;
  double ms = 0.0;
#pragma unroll
  for (int i = t; i < 1024; i += 256) ms += msep[i];
  if (t == 0) ms += *msedelta;

  double ent = 0.0;
  int used = 0;
#pragma unroll
  for (int i = t; i < KCB; i += 256) {
    int c = counts[i];
    if (c > 0) used++;
    double p = (double)c / (double)NROWS;
    ent += p * log(p + 1e-10);
  }
  __shared__ double se[256];
  __shared__ double sm[256];
  __shared__ int    su[256];
  se[t] = ent; sm[t] = ms; su[t] = used;
  __syncthreads();
  for (int s = 128; s > 0; s >>= 1) {
    if (t < s) { se[t] += se[t + s]; sm[t] += sm[t + s]; su[t] += su[t + s]; }
    __syncthreads();
  }
  if (t == 0) {
    double mse = sm[0] / ((double)NROWS * (double)DDIM);
    out[OUT_LOSS]  = (float)(1.25 * mse);
    out[OUT_PERP]  = (float)exp(-se[0]);
    out[OUT_USAGE] = (float)((double)su[0] / (double)KCB);
  }
}

// ---------------------------------------------------------------------------
extern "C" void kernel_launch(void* const* d_in, const int* in_sizes, int n_in,
                              void* d_out, int out_size, void* d_ws, size_t ws_size,
                              hipStream_t stream) {
  const float* z  = (const float*)d_in[0];   // [65536][256]
  const float* lb = (const float*)d_in[1];   // [1024][256]
  const float* W  = (const float*)d_in[2];   // [256][256]
  float* out = (float*)d_out;

  char* base = (char*)d_ws;
  double* cb64T   = (double*)(base + 0x000000);  // 2 MB (transposed [j][k])
  ushort* ch      = (ushort*)(base + 0x200000);  // 512 KB
  float*  cb32    = (float*) (base + 0x300000);  // 1 MB
  double* c264    = (double*)(base + 0x400000);  // 8 KB
  int*    idxi    = (int*)   (base + 0x402000);  // 256 KB
  int*    flagr   = (int*)   (base + 0x442000);  // 256 KB
  int*    counts  = (int*)   (base + 0x482000);  // 4 KB   } one zeroed
  int*    flagc   = (int*)   (base + 0x483000);  // 4 B    } contiguous
  double* msedel  = (double*)(base + 0x483008);  // 8 B    } region
  double* msep    = (double*)(base + 0x484000);  // 8 KB (1024 doubles)

  hipMemsetAsync(counts, 0, 0x1010, stream);     // counts + flagc + msedel

  cb_kernel<<<KCB, 256, 0, stream>>>(lb, W, cb64T, cb32, c264, ch);
  argmax_mfma<<<NROWS / 64, 256, 0, stream>>>(z, ch, cb32,
                                              out + OUT_IDX, idxi, flagc, flagr,
                                              out + OUT_ZQ, msep, counts);
  refine_kernel<<<512, 256, 0, stream>>>(z, cb64T, c264, cb32, flagc, flagr,
                                         idxi, out + OUT_IDX, out + OUT_ZQ,
                                         counts, msedel);
  finalize_kernel<<<1, 256, 0, stream>>>(counts, msep, msedel, out);
}

// Round 10
// 304.850 us; speedup vs baseline: 1.3641x; 1.3641x over previous
//
#include <hip/hip_runtime.h>
#include <math.h>

typedef unsigned int uint;
typedef unsigned short ushort;

#define NROWS 65536
#define KCB   1024
#define DDIM  256
#define MARGIN 0.15f

// d_out layout (floats)
#define OUT_ZQ    0
#define OUT_LOSS  16777216
#define OUT_IDX   16777217
#define OUT_PERP  16842753
#define OUT_USAGE 16842754

typedef __attribute__((ext_vector_type(8))) short s16x8;
typedef __attribute__((ext_vector_type(4))) float f32x4;
typedef __attribute__((ext_vector_type(4))) double f64x4;

__device__ __forceinline__ ushort bf16rne(float x) {
  uint u = __float_as_uint(x);
  return (ushort)((u + 0x7FFFu + ((u >> 16) & 1u)) >> 16);
}
__device__ __forceinline__ float bf2f(ushort h) {
  return __uint_as_float((uint)h << 16);
}

// ---------------------------------------------------------------------------
// Kernel 1: codebook = normalize(lb @ W.T) * 16 in fp64 (LDS-staged W);
// emits transposed fp64 (cb64T[j][k] for refine), fp32, and bf16-hi copy.
// ---------------------------------------------------------------------------
__global__ __launch_bounds__(256) void cb_kernel(const float* __restrict__ lb,
                                                 const float* __restrict__ W,
                                                 double* __restrict__ cb64T,
                                                 float* __restrict__ cb32,
                                                 double* __restrict__ c264,
                                                 ushort* __restrict__ ch) {
  const int k = blockIdx.x;
  const int t = threadIdx.x;
  __shared__ float lb_sh[256];
  __shared__ float W_sh[256 * 66];
  __shared__ double red[256];

  lb_sh[t] = lb[k * 256 + t];

  double acc = 0.0;
  for (int jt = 0; jt < 4; ++jt) {
    __syncthreads();
#pragma unroll
    for (int i = 0; i < 16; ++i) {
      int qid = t + 256 * i;
      int row = qid >> 4;
      int q   = qid & 15;
      float4 v = *(const float4*)&W[row * 256 + jt * 64 + q * 4];
      float* dst = &W_sh[row * 66 + q * 4];
      dst[0] = v.x; dst[1] = v.y; dst[2] = v.z; dst[3] = v.w;
    }
    __syncthreads();
#pragma unroll
    for (int jj = 0; jj < 64; ++jj) {
      acc += (double)lb_sh[jt * 64 + jj] * (double)W_sh[t * 66 + jj];
    }
  }

  red[t] = acc * acc;
  __syncthreads();
  for (int s = 128; s > 0; s >>= 1) {
    if (t < s) red[t] += red[t + s];
    __syncthreads();
  }
  double norm  = sqrt(red[0]);
  double scale = 16.0 / fmax(norm, 1e-12);
  double v     = acc * scale;
  cb64T[(size_t)t * 1024 + k] = v;        // transposed for refine
  float cf = (float)v;
  cb32[k * 256 + t] = cf;
  ch[k * 256 + t] = bf16rne(cf);

  __syncthreads();
  red[t] = v * v;
  __syncthreads();
  for (int s = 128; s > 0; s >>= 1) {
    if (t < s) red[t] += red[t + s];
    __syncthreads();
  }
  if (t == 0) c264[k] = red[0];
}

// ---------------------------------------------------------------------------
// Kernel 2: fused MFMA argmax + gather, 16x16x32 (unchanged from round 9 --
// ~100us, verified). score = (zh + zl) . ch; MARGIN 0.15 + exact refine.
// ---------------------------------------------------------------------------
__global__ __launch_bounds__(256, 4) void argmax_mfma(const float* __restrict__ z,
                                                      const ushort* __restrict__ ch,
                                                      const float* __restrict__ cb32,
                                                      float* __restrict__ out_idx,
                                                      int* __restrict__ idx_int,
                                                      int* __restrict__ flagc,
                                                      int* __restrict__ flagr,
                                                      float* __restrict__ zq,
                                                      double* __restrict__ msep,
                                                      int* __restrict__ counts) {
  const int t     = threadIdx.x;
  const int lane  = t & 63;
  const int w     = t >> 6;
  const int ra    = lane & 15;     // z-row within wave
  const int q4    = lane >> 4;     // K-quarter (8 bf16 each)
  const int mtile = blockIdx.x;

  __shared__ alignas(128) char cbuf[2][8192];
  __shared__ int    sidx[64];
  __shared__ double partial[4];

  // ---- z fragments: one z-row per lane, fp32 -> bf16 hi/lo in-register ----
  s16x8 zh[8], zl[8];
  const int zrow = mtile * 64 + w * 16 + ra;
#pragma unroll
  for (int c = 0; c < 8; ++c) {
    const float* zp = &z[(size_t)zrow * 256 + c * 32 + q4 * 8];
    float4 f0 = *(const float4*)zp;
    float4 f1 = *(const float4*)(zp + 4);
    float xs[8] = {f0.x, f0.y, f0.z, f0.w, f1.x, f1.y, f1.z, f1.w};
#pragma unroll
    for (int e = 0; e < 8; ++e) {
      ushort hh = bf16rne(xs[e]);
      zh[c][e] = (short)hh;
      zl[c][e] = (short)bf16rne(xs[e] - bf2f(hh));
    }
  }

  // ---- staging: 512 slots of 16B; slot s: kc=s>>8, q=(s>>6)&3, row=s&63.
  //      Linear LDS dest (wave-uniform base), per-lane global source. ----
  auto stage = [&](int buf, int nt, int kt2) {
#pragma unroll
    for (int j = 0; j < 2; ++j) {
      int s   = w * 128 + j * 64 + lane;
      int kc  = s >> 8;
      int q   = (s >> 6) & 3;
      int row = s & 63;
      const ushort* src = ch + (size_t)(nt * 64 + row) * 256 + kt2 * 64 + kc * 32 + q * 8;
      __builtin_amdgcn_global_load_lds(
          (const __attribute__((address_space(1))) void*)src,
          (__attribute__((address_space(3))) void*)(&cbuf[buf][0] + (w * 128 + j * 64) * 16),
          16, 0, 0);
    }
  };

  float m1 = -3.0e38f, m2 = -3.0e38f;
  int   i1 = 0;

  stage(0, 0, 0);
  __syncthreads();

#pragma unroll 1
  for (int nt = 0; nt < 16; ++nt) {
    f32x4 acc[4] = {f32x4(0.0f), f32x4(0.0f), f32x4(0.0f), f32x4(0.0f)};
#pragma unroll
    for (int kt2 = 0; kt2 < 4; ++kt2) {
      const int cur = (nt * 4 + kt2) & 1;
      if (kt2 < 3)      stage(cur ^ 1, nt, kt2 + 1);
      else if (nt < 15) stage(cur ^ 1, nt + 1, 0);

      const char* cbb = &cbuf[cur][0];
#pragma unroll
      for (int kc = 0; kc < 2; ++kc) {
        const s16x8 bh = zh[kt2 * 2 + kc];
        const s16x8 bl = zl[kt2 * 2 + kc];
#pragma unroll
        for (int cg = 0; cg < 4; ++cg) {
          s16x8 a = *(const s16x8*)(cbb + kc * 4096 + q4 * 1024 + (cg * 16 + ra) * 16);
          acc[cg] = __builtin_amdgcn_mfma_f32_16x16x32_bf16(a, bh, acc[cg], 0, 0, 0);
          acc[cg] = __builtin_amdgcn_mfma_f32_16x16x32_bf16(a, bl, acc[cg], 0, 0, 0);
        }
      }
      __syncthreads();
    }

    // fold this nt's 64 codes into the lane's (m1, m2, i1).
#pragma unroll
    for (int cg = 0; cg < 4; ++cg) {
#pragma unroll
      for (int j = 0; j < 4; ++j) {
        const int code = nt * 64 + cg * 16 + q4 * 4 + j;
        float v = acc[cg][j];
        if (v > m1) { m2 = m1; m1 = v; i1 = code; }
        else        { m2 = fmaxf(m2, v); }
      }
    }
  }

  // ---- cross-lane merge across the 4 K-quarter copies of each z-row ----
#pragma unroll
  for (int off = 16; off <= 32; off <<= 1) {
    float om1 = __shfl_xor(m1, off);
    float om2 = __shfl_xor(m2, off);
    int   oi1 = __shfl_xor(i1, off);
    if (om1 > m1 || (om1 == m1 && oi1 < i1)) {
      m2 = fmaxf(m1, om2); m1 = om1; i1 = oi1;
    } else {
      m2 = fmaxf(m2, om1);
    }
  }

  if (lane < 16) {
    const int row = mtile * 64 + w * 16 + lane;
    sidx[w * 16 + lane] = i1;
    idx_int[row] = i1;
    out_idx[row] = (float)i1;
    if (m1 - m2 < MARGIN) {
      int pos = atomicAdd(flagc, 1);
      flagr[pos] = row;
    }
  }
  __syncthreads();

  // ---- fused gather: z_q write, mse partial, counts ----
  double msum = 0.0;
  for (int rr = w; rr < 64; rr += 4) {
    const int code = sidx[rr];
    const int grow = mtile * 64 + rr;
    float4 c = *(const float4*)&cb32[(size_t)code * 256 + lane * 4];
    *(float4*)&zq[(size_t)grow * 256 + lane * 4] = c;
    float4 zr = *(const float4*)&z[(size_t)grow * 256 + lane * 4];
    double d;
    d = (double)c.x - (double)zr.x; msum += d * d;
    d = (double)c.y - (double)zr.y; msum += d * d;
    d = (double)c.z - (double)zr.z; msum += d * d;
    d = (double)c.w - (double)zr.w; msum += d * d;
    if (lane == 0) atomicAdd(&counts[code], 1);
  }
#pragma unroll
  for (int off = 32; off > 0; off >>= 1) msum += __shfl_xor(msum, off);
  if (lane == 0) partial[w] = msum;
  __syncthreads();
  if (t == 0) msep[mtile] = partial[0] + partial[1] + partial[2] + partial[3];
}

// ---------------------------------------------------------------------------
// Kernel 3: exact fp64 re-solve of flagged rows (round-10 throughput fix).
// Thread t owns codes 4t..4t+3 -> ONE double4 (32B) load per j (2x dwordx4,
// coalesced 8KB/block); j-loop unrolled x8 so 8 loads are in flight before
// the FMA chain (round 9: four 8B loads/j, no pipelining, 286us latency-
// bound). Grid 1024. Patches idx, z_q, counts, mse delta on index change.
// ---------------------------------------------------------------------------
__global__ __launch_bounds__(256) void refine_kernel(const float* __restrict__ z,
                                                     const double* __restrict__ cb64T,
                                                     const double* __restrict__ c264,
                                                     const float* __restrict__ cb32,
                                                     const int* __restrict__ flagc,
                                                     const int* __restrict__ flagr,
                                                     int* __restrict__ idx_int,
                                                     float* __restrict__ out_idx,
                                                     float* __restrict__ zq,
                                                     int* __restrict__ counts,
                                                     double* __restrict__ msedelta) {
  const int cnt = *flagc;
  const int t   = threadIdx.x;
  __shared__ double z_sh[256];
  __shared__ double rs[256];
  __shared__ int    ri[256];
  __shared__ int    shI, shO;
  __shared__ double red[256];

  for (int fi = blockIdx.x; fi < cnt; fi += gridDim.x) {
    const int row = flagr[fi];
    __syncthreads();
    z_sh[t] = (double)z[(size_t)row * DDIM + t];
    __syncthreads();

    double a0 = 0.0, a1 = 0.0, a2 = 0.0, a3 = 0.0;
#pragma unroll 1
    for (int jb = 0; jb < 256; jb += 8) {
      f64x4 cv[8];
      double zv[8];
#pragma unroll
      for (int u = 0; u < 8; ++u) {
        cv[u] = *(const f64x4*)&cb64T[(size_t)(jb + u) * 1024 + t * 4];
        zv[u] = z_sh[jb + u];
      }
#pragma unroll
      for (int u = 0; u < 8; ++u) {
        a0 += zv[u] * cv[u][0];
        a1 += zv[u] * cv[u][1];
        a2 += zv[u] * cv[u][2];
        a3 += zv[u] * cv[u][3];
      }
    }
    f64x4 c2 = *(const f64x4*)&c264[t * 4];
    double b  = 2.0 * a0 - c2[0];  int bi_ = t * 4;
    double s1 = 2.0 * a1 - c2[1];  if (s1 > b) { b = s1; bi_ = t * 4 + 1; }
    double s2 = 2.0 * a2 - c2[2];  if (s2 > b) { b = s2; bi_ = t * 4 + 2; }
    double s3 = 2.0 * a3 - c2[3];  if (s3 > b) { b = s3; bi_ = t * 4 + 3; }
    rs[t] = b; ri[t] = bi_;
    __syncthreads();
    for (int s = 128; s > 0; s >>= 1) {
      if (t < s) {
        if (rs[t + s] > rs[t] || (rs[t + s] == rs[t] && ri[t + s] < ri[t])) {
          rs[t] = rs[t + s]; ri[t] = ri[t + s];
        }
      }
      __syncthreads();
    }
    if (t == 0) {
      int I = ri[0];
      shO = idx_int[row];
      shI = I;
      if (I != shO) {
        idx_int[row] = I;
        out_idx[row] = (float)I;
        atomicSub(&counts[shO], 1);
        atomicAdd(&counts[I], 1);
      }
    }
    __syncthreads();
    const int I = shI, O = shO;
    if (I != O) {
      float zz = z[(size_t)row * DDIM + t];
      float cn = cb32[(size_t)I * DDIM + t];
      float co = cb32[(size_t)O * DDIM + t];
      zq[(size_t)row * DDIM + t] = cn;
      double dn = (double)cn - (double)zz;
      double dd = (double)co - (double)zz;
      red[t] = dn * dn - dd * dd;
      __syncthreads();
      for (int s = 128; s > 0; s >>= 1) {
        if (t < s) red[t] += red[t + s];
        __syncthreads();
      }
      if (t == 0) atomicAdd(msedelta, red[0]);
    }
    __syncthreads();
  }
}

// ---------------------------------------------------------------------------
// Kernel 4: scalars -- vq_loss, perplexity, codebook_usage.
// ---------------------------------------------------------------------------
__global__ __launch_bounds__(256) void finalize_kernel(const int* __restrict__ counts,
                                                       const double* __restrict__ msep,
                                                       const double* __restrict__ msedelta,
                                                       float* __restrict__ out) {
  const int t = threadIdx.x;
  double ms = 0.0;
#pragma unroll
  for (int i = t; i < 1024; i += 256) ms += msep[i];
  if (t == 0) ms += *msedelta;

  double ent = 0.0;
  int used = 0;
#pragma unroll
  for (int i = t; i < KCB; i += 256) {
    int c = counts[i];
    if (c > 0) used++;
    double p = (double)c / (double)NROWS;
    ent += p * log(p + 1e-10);
  }
  __shared__ double se[256];
  __shared__ double sm[256];
  __shared__ int    su[256];
  se[t] = ent; sm[t] = ms; su[t] = used;
  __syncthreads();
  for (int s = 128; s > 0; s >>= 1) {
    if (t < s) { se[t] += se[t + s]; sm[t] += sm[t + s]; su[t] += su[t + s]; }
    __syncthreads();
  }
  if (t == 0) {
    double mse = sm[0] / ((double)NROWS * (double)DDIM);
    out[OUT_LOSS]  = (float)(1.25 * mse);
    out[OUT_PERP]  = (float)exp(-se[0]);
    out[OUT_USAGE] = (float)((double)su[0] / (double)KCB);
  }
}

// ---------------------------------------------------------------------------
extern "C" void kernel_launch(void* const* d_in, const int* in_sizes, int n_in,
                              void* d_out, int out_size, void* d_ws, size_t ws_size,
                              hipStream_t stream) {
  const float* z  = (const float*)d_in[0];   // [65536][256]
  const float* lb = (const float*)d_in[1];   // [1024][256]
  const float* W  = (const float*)d_in[2];   // [256][256]
  float* out = (float*)d_out;

  char* base = (char*)d_ws;
  double* cb64T   = (double*)(base + 0x000000);  // 2 MB (transposed [j][k])
  ushort* ch      = (ushort*)(base + 0x200000);  // 512 KB
  float*  cb32    = (float*) (base + 0x300000);  // 1 MB
  double* c264    = (double*)(base + 0x400000);  // 8 KB
  int*    idxi    = (int*)   (base + 0x402000);  // 256 KB
  int*    flagr   = (int*)   (base + 0x442000);  // 256 KB
  int*    counts  = (int*)   (base + 0x482000);  // 4 KB   } one zeroed
  int*    flagc   = (int*)   (base + 0x483000);  // 4 B    } contiguous
  double* msedel  = (double*)(base + 0x483008);  // 8 B    } region
  double* msep    = (double*)(base + 0x484000);  // 8 KB (1024 doubles)

  hipMemsetAsync(counts, 0, 0x1010, stream);     // counts + flagc + msedel

  cb_kernel<<<KCB, 256, 0, stream>>>(lb, W, cb64T, cb32, c264, ch);
  argmax_mfma<<<NROWS / 64, 256, 0, stream>>>(z, ch, cb32,
                                              out + OUT_IDX, idxi, flagc, flagr,
                                              out + OUT_ZQ, msep, counts);
  refine_kernel<<<1024, 256, 0, stream>>>(z, cb64T, c264, cb32, flagc, flagr,
                                          idxi, out + OUT_IDX, out + OUT_ZQ,
                                          counts, msedel);
  finalize_kernel<<<1, 256, 0, stream>>>(counts, msep, msedel, out);
}

// Round 11
// 263.032 us; speedup vs baseline: 1.5810x; 1.1590x over previous
//
#include <hip/hip_runtime.h>
#include <math.h>

typedef unsigned int uint;
typedef unsigned short ushort;

#define NROWS 65536
#define KCB   1024
#define DDIM  256
#define MARGIN 0.15f

// d_out layout (floats)
#define OUT_ZQ    0
#define OUT_LOSS  16777216
#define OUT_IDX   16777217
#define OUT_PERP  16842753
#define OUT_USAGE 16842754

typedef __attribute__((ext_vector_type(8))) short s16x8;
typedef __attribute__((ext_vector_type(4))) float f32x4;
typedef __attribute__((ext_vector_type(4))) double f64x4;

__device__ __forceinline__ ushort bf16rne(float x) {
  uint u = __float_as_uint(x);
  return (ushort)((u + 0x7FFFu + ((u >> 16) & 1u)) >> 16);
}
__device__ __forceinline__ float bf2f(ushort h) {
  return __uint_as_float((uint)h << 16);
}

// ---------------------------------------------------------------------------
// Kernel 1: codebook = normalize(lb @ W.T) * 16 in fp64 (LDS-staged W);
// emits transposed fp64 (cb64T[j][k] for refine), fp32, and bf16-hi copy.
// ---------------------------------------------------------------------------
__global__ __launch_bounds__(256) void cb_kernel(const float* __restrict__ lb,
                                                 const float* __restrict__ W,
                                                 double* __restrict__ cb64T,
                                                 float* __restrict__ cb32,
                                                 double* __restrict__ c264,
                                                 ushort* __restrict__ ch) {
  const int k = blockIdx.x;
  const int t = threadIdx.x;
  __shared__ float lb_sh[256];
  __shared__ float W_sh[256 * 66];
  __shared__ double red[256];

  lb_sh[t] = lb[k * 256 + t];

  double acc = 0.0;
  for (int jt = 0; jt < 4; ++jt) {
    __syncthreads();
#pragma unroll
    for (int i = 0; i < 16; ++i) {
      int qid = t + 256 * i;
      int row = qid >> 4;
      int q   = qid & 15;
      float4 v = *(const float4*)&W[row * 256 + jt * 64 + q * 4];
      float* dst = &W_sh[row * 66 + q * 4];
      dst[0] = v.x; dst[1] = v.y; dst[2] = v.z; dst[3] = v.w;
    }
    __syncthreads();
#pragma unroll
    for (int jj = 0; jj < 64; ++jj) {
      acc += (double)lb_sh[jt * 64 + jj] * (double)W_sh[t * 66 + jj];
    }
  }

  red[t] = acc * acc;
  __syncthreads();
  for (int s = 128; s > 0; s >>= 1) {
    if (t < s) red[t] += red[t + s];
    __syncthreads();
  }
  double norm  = sqrt(red[0]);
  double scale = 16.0 / fmax(norm, 1e-12);
  double v     = acc * scale;
  cb64T[(size_t)t * 1024 + k] = v;        // transposed for refine
  float cf = (float)v;
  cb32[k * 256 + t] = cf;
  ch[k * 256 + t] = bf16rne(cf);

  __syncthreads();
  red[t] = v * v;
  __syncthreads();
  for (int s = 128; s > 0; s >>= 1) {
    if (t < s) red[t] += red[t + s];
    __syncthreads();
  }
  if (t == 0) c264[k] = red[0];
}

// ---------------------------------------------------------------------------
// Kernel 2: fused MFMA argmax + gather, 16x16x32 (round-11).
// score = (zh + zl) . ch; MARGIN 0.15 + exact refine.
// Change vs round 9/10: K-tile doubled to 64 codes x 128 k (16 KB, 2 buffers
// = 32 KB LDS, still 4 blocks/CU) -> 32 barriers instead of 64, with
// 16 ds_read + 32 MFMA + 4 gload_lds per barrier. K-major conflict-free
// layout and linear gload_lds dest unchanged.
// ---------------------------------------------------------------------------
__global__ __launch_bounds__(256, 4) void argmax_mfma(const float* __restrict__ z,
                                                      const ushort* __restrict__ ch,
                                                      const float* __restrict__ cb32,
                                                      float* __restrict__ out_idx,
                                                      int* __restrict__ idx_int,
                                                      int* __restrict__ flagc,
                                                      int* __restrict__ flagr,
                                                      float* __restrict__ zq,
                                                      double* __restrict__ msep,
                                                      int* __restrict__ counts) {
  const int t     = threadIdx.x;
  const int lane  = t & 63;
  const int w     = t >> 6;
  const int ra    = lane & 15;     // z-row within wave
  const int q4    = lane >> 4;     // K 8-elem subchunk within a 32-k chunk
  const int mtile = blockIdx.x;

  __shared__ alignas(128) char cbuf[2][16384];
  __shared__ int    sidx[64];
  __shared__ double partial[4];

  // ---- z fragments: one z-row per lane, fp32 -> bf16 hi/lo in-register ----
  s16x8 zh[8], zl[8];
  const int zrow = mtile * 64 + w * 16 + ra;
#pragma unroll
  for (int c = 0; c < 8; ++c) {
    const float* zp = &z[(size_t)zrow * 256 + c * 32 + q4 * 8];
    float4 f0 = *(const float4*)zp;
    float4 f1 = *(const float4*)(zp + 4);
    float xs[8] = {f0.x, f0.y, f0.z, f0.w, f1.x, f1.y, f1.z, f1.w};
#pragma unroll
    for (int e = 0; e < 8; ++e) {
      ushort hh = bf16rne(xs[e]);
      zh[c][e] = (short)hh;
      zl[c][e] = (short)bf16rne(xs[e] - bf2f(hh));
    }
  }

  // ---- staging: 1024 slots of 16B; slot s: kc=s>>8, q=(s>>6)&3, row=s&63.
  //      Linear LDS dest (wave-uniform base + lane*16), per-lane source. ----
  auto stage = [&](int buf, int nt, int kt) {
#pragma unroll
    for (int j = 0; j < 4; ++j) {
      int s   = w * 256 + j * 64 + lane;
      int kc  = s >> 8;
      int q   = (s >> 6) & 3;
      int row = s & 63;
      const ushort* src = ch + (size_t)(nt * 64 + row) * 256 + kt * 128 + kc * 32 + q * 8;
      __builtin_amdgcn_global_load_lds(
          (const __attribute__((address_space(1))) void*)src,
          (__attribute__((address_space(3))) void*)(&cbuf[buf][0] + (w * 256 + j * 64) * 16),
          16, 0, 0);
    }
  };

  float m1 = -3.0e38f, m2 = -3.0e38f;
  int   i1 = 0;

  stage(0, 0, 0);
  __syncthreads();

#pragma unroll 1
  for (int nt = 0; nt < 16; ++nt) {
    f32x4 acc[4] = {f32x4(0.0f), f32x4(0.0f), f32x4(0.0f), f32x4(0.0f)};
#pragma unroll
    for (int kt = 0; kt < 2; ++kt) {
      const int cur = (nt * 2 + kt) & 1;
      if (kt == 0)      stage(cur ^ 1, nt, 1);
      else if (nt < 15) stage(cur ^ 1, nt + 1, 0);

      const char* cbb = &cbuf[cur][0];
#pragma unroll
      for (int kc = 0; kc < 4; ++kc) {
        const s16x8 bh = zh[kt * 4 + kc];
        const s16x8 bl = zl[kt * 4 + kc];
#pragma unroll
        for (int cg = 0; cg < 4; ++cg) {
          s16x8 a = *(const s16x8*)(cbb + kc * 4096 + q4 * 1024 + (cg * 16 + ra) * 16);
          acc[cg] = __builtin_amdgcn_mfma_f32_16x16x32_bf16(a, bh, acc[cg], 0, 0, 0);
          acc[cg] = __builtin_amdgcn_mfma_f32_16x16x32_bf16(a, bl, acc[cg], 0, 0, 0);
        }
      }
      __syncthreads();
    }

    // fold this nt's 64 codes into the lane's (m1, m2, i1).
    // D layout (m89/m91): col = lane&15 = zrow; code = cg*16 + q4*4 + j.
#pragma unroll
    for (int cg = 0; cg < 4; ++cg) {
#pragma unroll
      for (int j = 0; j < 4; ++j) {
        const int code = nt * 64 + cg * 16 + q4 * 4 + j;
        float v = acc[cg][j];
        if (v > m1) { m2 = m1; m1 = v; i1 = code; }
        else        { m2 = fmaxf(m2, v); }
      }
    }
  }

  // ---- cross-lane merge across the 4 K-quarter copies of each z-row ----
#pragma unroll
  for (int off = 16; off <= 32; off <<= 1) {
    float om1 = __shfl_xor(m1, off);
    float om2 = __shfl_xor(m2, off);
    int   oi1 = __shfl_xor(i1, off);
    if (om1 > m1 || (om1 == m1 && oi1 < i1)) {
      m2 = fmaxf(m1, om2); m1 = om1; i1 = oi1;
    } else {
      m2 = fmaxf(m2, om1);
    }
  }

  if (lane < 16) {
    const int row = mtile * 64 + w * 16 + lane;
    sidx[w * 16 + lane] = i1;
    idx_int[row] = i1;
    out_idx[row] = (float)i1;
    if (m1 - m2 < MARGIN) {
      int pos = atomicAdd(flagc, 1);
      flagr[pos] = row;
    }
  }
  __syncthreads();

  // ---- fused gather: z_q write, mse partial, counts ----
  double msum = 0.0;
  for (int rr = w; rr < 64; rr += 4) {
    const int code = sidx[rr];
    const int grow = mtile * 64 + rr;
    float4 c = *(const float4*)&cb32[(size_t)code * 256 + lane * 4];
    *(float4*)&zq[(size_t)grow * 256 + lane * 4] = c;
    float4 zr = *(const float4*)&z[(size_t)grow * 256 + lane * 4];
    double d;
    d = (double)c.x - (double)zr.x; msum += d * d;
    d = (double)c.y - (double)zr.y; msum += d * d;
    d = (double)c.z - (double)zr.z; msum += d * d;
    d = (double)c.w - (double)zr.w; msum += d * d;
    if (lane == 0) atomicAdd(&counts[code], 1);
  }
#pragma unroll
  for (int off = 32; off > 0; off >>= 1) msum += __shfl_xor(msum, off);
  if (lane == 0) partial[w] = msum;
  __syncthreads();
  if (t == 0) msep[mtile] = partial[0] + partial[1] + partial[2] + partial[3];
}

// ---------------------------------------------------------------------------
// Kernel 3: exact fp64 re-solve of flagged rows (round-11: 8-row batching).
// Round 10 streamed the full 2MB cb64T from L2 PER ROW (~5 GB total, L2-BW
// bound at 172us). Now each cb64T double4 load feeds 8 rows x 4 codes = 32
// f64 FMA (traffic /8, compute-bound ~17us). Accumulators fully unrolled
// static arrays (rule 20). Patches idx, z_q, counts, mse delta per row.
// ---------------------------------------------------------------------------
__global__ __launch_bounds__(256) void refine_kernel(const float* __restrict__ z,
                                                     const double* __restrict__ cb64T,
                                                     const double* __restrict__ c264,
                                                     const float* __restrict__ cb32,
                                                     const int* __restrict__ flagc,
                                                     const int* __restrict__ flagr,
                                                     int* __restrict__ idx_int,
                                                     float* __restrict__ out_idx,
                                                     float* __restrict__ zq,
                                                     int* __restrict__ counts,
                                                     double* __restrict__ msedelta) {
  const int cnt = *flagc;
  const int t   = threadIdx.x;
  __shared__ double z_sh[8][256];
  __shared__ double rs[256];
  __shared__ int    ri[256];
  __shared__ int    shI, shO;
  __shared__ double red[256];

  const int nbatch = (cnt + 7) >> 3;
  for (int b = blockIdx.x; b < nbatch; b += gridDim.x) {
    const int r0 = b * 8;
    const int nr = min(8, cnt - r0);
    __syncthreads();   // z_sh reuse across batches
#pragma unroll
    for (int r = 0; r < 8; ++r) {
      int rr = (r < nr) ? flagr[r0 + r] : flagr[r0];
      z_sh[r][t] = (double)z[(size_t)rr * DDIM + t];
    }
    __syncthreads();

    double a0[8], a1[8], a2[8], a3[8];
#pragma unroll
    for (int r = 0; r < 8; ++r) { a0[r] = 0.0; a1[r] = 0.0; a2[r] = 0.0; a3[r] = 0.0; }

#pragma unroll 1
    for (int j = 0; j < 256; j += 2) {
      f64x4 cv0 = *(const f64x4*)&cb64T[(size_t)j * 1024 + t * 4];
      f64x4 cv1 = *(const f64x4*)&cb64T[(size_t)(j + 1) * 1024 + t * 4];
#pragma unroll
      for (int r = 0; r < 8; ++r) {
        double zv = z_sh[r][j];
        a0[r] += zv * cv0[0];
        a1[r] += zv * cv0[1];
        a2[r] += zv * cv0[2];
        a3[r] += zv * cv0[3];
      }
#pragma unroll
      for (int r = 0; r < 8; ++r) {
        double zv = z_sh[r][j + 1];
        a0[r] += zv * cv1[0];
        a1[r] += zv * cv1[1];
        a2[r] += zv * cv1[2];
        a3[r] += zv * cv1[3];
      }
    }

    f64x4 c2 = *(const f64x4*)&c264[t * 4];
#pragma unroll
    for (int r = 0; r < 8; ++r) {
      if (r >= nr) continue;     // nr is block-uniform -> barriers legal
      double bb = 2.0 * a0[r] - c2[0];  int bi_ = t * 4;
      double s1 = 2.0 * a1[r] - c2[1];  if (s1 > bb) { bb = s1; bi_ = t * 4 + 1; }
      double s2 = 2.0 * a2[r] - c2[2];  if (s2 > bb) { bb = s2; bi_ = t * 4 + 2; }
      double s3 = 2.0 * a3[r] - c2[3];  if (s3 > bb) { bb = s3; bi_ = t * 4 + 3; }
      rs[t] = bb; ri[t] = bi_;
      __syncthreads();
      for (int s = 128; s > 0; s >>= 1) {
        if (t < s) {
          if (rs[t + s] > rs[t] || (rs[t + s] == rs[t] && ri[t + s] < ri[t])) {
            rs[t] = rs[t + s]; ri[t] = ri[t + s];
          }
        }
        __syncthreads();
      }
      const int row = flagr[r0 + r];
      if (t == 0) {
        int I = ri[0];
        shO = idx_int[row];
        shI = I;
        if (I != shO) {
          idx_int[row] = I;
          out_idx[row] = (float)I;
          atomicSub(&counts[shO], 1);
          atomicAdd(&counts[I], 1);
        }
      }
      __syncthreads();
      const int I = shI, O = shO;
      if (I != O) {
        float zz = (float)z_sh[r][t];
        float cn = cb32[(size_t)I * DDIM + t];
        float co = cb32[(size_t)O * DDIM + t];
        zq[(size_t)row * DDIM + t] = cn;
        double dn = (double)cn - (double)zz;
        double dd = (double)co - (double)zz;
        red[t] = dn * dn - dd * dd;
        __syncthreads();
        for (int s = 128; s > 0; s >>= 1) {
          if (t < s) red[t] += red[t + s];
          __syncthreads();
        }
        if (t == 0) atomicAdd(msedelta, red[0]);
      }
      __syncthreads();
    }
  }
}

// ---------------------------------------------------------------------------
// Kernel 4: scalars -- vq_loss, perplexity, codebook_usage.
// ---------------------------------------------------------------------------
__global__ __launch_bounds__(256) void finalize_kernel(const int* __restrict__ counts,
                                                       const double* __restrict__ msep,
                                                       const double* __restrict__ msedelta,
                                                       float* __restrict__ out) {
  const int t = threadIdx.x;
  double ms = 0.0;
#pragma unroll
  for (int i = t; i < 1024; i += 256) ms += msep[i];
  if (t == 0) ms += *msedelta;

  double ent = 0.0;
  int used = 0;
#pragma unroll
  for (int i = t; i < KCB; i += 256) {
    int c = counts[i];
    if (c > 0) used++;
    double p = (double)c / (double)NROWS;
    ent += p * log(p + 1e-10);
  }
  __shared__ double se[256];
  __shared__ double sm[256];
  __shared__ int    su[256];
  se[t] = ent; sm[t] = ms; su[t] = used;
  __syncthreads();
  for (int s = 128; s > 0; s >>= 1) {
    if (t < s) { se[t] += se[t + s]; sm[t] += sm[t + s]; su[t] += su[t + s]; }
    __syncthreads();
  }
  if (t == 0) {
    double mse = sm[0] / ((double)NROWS * (double)DDIM);
    out[OUT_LOSS]  = (float)(1.25 * mse);
    out[OUT_PERP]  = (float)exp(-se[0]);
    out[OUT_USAGE] = (float)((double)su[0] / (double)KCB);
  }
}

// ---------------------------------------------------------------------------
extern "C" void kernel_launch(void* const* d_in, const int* in_sizes, int n_in,
                              void* d_out, int out_size, void* d_ws, size_t ws_size,
                              hipStream_t stream) {
  const float* z  = (const float*)d_in[0];   // [65536][256]
  const float* lb = (const float*)d_in[1];   // [1024][256]
  const float* W  = (const float*)d_in[2];   // [256][256]
  float* out = (float*)d_out;

  char* base = (char*)d_ws;
  double* cb64T   = (double*)(base + 0x000000);  // 2 MB (transposed [j][k])
  ushort* ch      = (ushort*)(base + 0x200000);  // 512 KB
  float*  cb32    = (float*) (base + 0x300000);  // 1 MB
  double* c264    = (double*)(base + 0x400000);  // 8 KB
  int*    idxi    = (int*)   (base + 0x402000);  // 256 KB
  int*    flagr   = (int*)   (base + 0x442000);  // 256 KB
  int*    counts  = (int*)   (base + 0x482000);  // 4 KB   } one zeroed
  int*    flagc   = (int*)   (base + 0x483000);  // 4 B    } contiguous
  double* msedel  = (double*)(base + 0x483008);  // 8 B    } region
  double* msep    = (double*)(base + 0x484000);  // 8 KB (1024 doubles)

  hipMemsetAsync(counts, 0, 0x1010, stream);     // counts + flagc + msedel

  cb_kernel<<<KCB, 256, 0, stream>>>(lb, W, cb64T, cb32, c264, ch);
  argmax_mfma<<<NROWS / 64, 256, 0, stream>>>(z, ch, cb32,
                                              out + OUT_IDX, idxi, flagc, flagr,
                                              out + OUT_ZQ, msep, counts);
  refine_kernel<<<1024, 256, 0, stream>>>(z, cb64T, c264, cb32, flagc, flagr,
                                          idxi, out + OUT_IDX, out + OUT_ZQ,
                                          counts, msedel);
  finalize_kernel<<<1, 256, 0, stream>>>(counts, msep, msedel, out);
}